// Round 9
// baseline (104.991 us; speedup 1.0000x reference)
//
#include <hip/hip_runtime.h>
#include <cstdint>
#include <cstddef>

typedef __bf16 bf16x8 __attribute__((ext_vector_type(8)));
typedef float f32x4 __attribute__((ext_vector_type(4)));

#define L_SEQ 32768
#define H_DIM 512
#define P_DIM 256
#define NP2   512      // 2P = K and N of both GEMMs
#define CHUNK 32
#define NCHUNK 1024    // L / CHUNK
#define NSUPER 32      // NCHUNK / 32

__device__ __forceinline__ void gload_lds16(const void* g, void* l) {
    __builtin_amdgcn_global_load_lds(
        (const __attribute__((address_space(1))) void*)g,
        (__attribute__((address_space(3))) void*)l,
        16, 0, 0);
}

// ---------------- per-channel parameter precompute ----------------
// par layout (floats): [0]=Ar [256]=Ai [512]=coefR [768]=coefI
//                      [1024]=PowR (Lbar^32) [1280]=PowI
//                      [1536]=ldr (Re(Lambda)*step) [1792]=ldi (Im(Lambda)*step)
__global__ void prep_kernel(const float* __restrict__ Lre, const float* __restrict__ Lim,
                            const float* __restrict__ lstep, float* __restrict__ par) {
    int p = threadIdx.x;
    if (p >= P_DIM) return;
    float lr = fminf(Lre[p], -1e-4f);       // clip_eigs
    float li = Lim[p];
    float st = expf(lstep[p]);
    float ldr = lr * st;
    float ldi = li * st;
    float er = expf(ldr);
    float ar = er * cosf(ldi);
    float ai = er * sinf(ldi);
    // coeff = (Lambda_bar - 1) / Lambda
    float den = lr * lr + li * li;
    float mr = ar - 1.0f, mi = ai;
    float cr = (mr * lr + mi * li) / den;
    float ci = (mi * lr - mr * li) / den;
    // Lambda_bar^CHUNK = exp(CHUNK * Lambda * step)
    float e32  = expf((float)CHUNK * ldr);
    float ph32 = (float)CHUNK * ldi;
    float pr = e32 * cosf(ph32);
    float pi = e32 * sinf(ph32);
    par[p] = ar;        par[256 + p] = ai;
    par[512 + p] = cr;  par[768 + p] = ci;
    par[1024 + p] = pr; par[1280 + p] = pi;
    par[1536 + p] = ldr; par[1792 + p] = ldi;
}

// Merged B/C builders. Blocks [0,512): Bt[n][k] (re rows 0..255, im rows 256..511).
// Blocks [512,1024): Ct[h][q] with 2x / -2x signs folded.
__global__ void build_BC_kernel(const float* __restrict__ Bre, const float* __restrict__ Bim,
                                const float* __restrict__ par,
                                const float* __restrict__ Cre, const float* __restrict__ Cim,
                                __bf16* __restrict__ Bt, __bf16* __restrict__ Ct) {
    int b = blockIdx.x;
    if (b < 512) {
        int idx = b * 256 + threadIdx.x;       // [0, P*H)
        int p = idx >> 9;
        float cr = par[512 + p], ci = par[768 + p];
        float br = Bre[idx], bi = Bim[idx];
        int h = idx & 511;
        Bt[(size_t)p * NP2 + h]         = (__bf16)(cr * br - ci * bi);
        Bt[(size_t)(256 + p) * NP2 + h] = (__bf16)(cr * bi + ci * br);
    } else {
        int idx = (b - 512) * 256 + threadIdx.x;   // [0, H*P)
        int h = idx >> 8;
        int q = idx & 255;
        Ct[(size_t)h * NP2 + q]       = (__bf16)( 2.0f * Cre[idx]);
        Ct[(size_t)h * NP2 + 256 + q] = (__bf16)(-2.0f * Cim[idx]);
    }
}

__global__ void cast_u_kernel(const float4* __restrict__ in, bf16x8* __restrict__ out, int n8) {
    int i = blockIdx.x * blockDim.x + threadIdx.x;
    if (i >= n8) return;
    float4 a = in[2 * i], b = in[2 * i + 1];
    bf16x8 v;
    v[0] = (__bf16)a.x; v[1] = (__bf16)a.y; v[2] = (__bf16)a.z; v[3] = (__bf16)a.w;
    v[4] = (__bf16)b.x; v[5] = (__bf16)b.y; v[6] = (__bf16)b.z; v[7] = (__bf16)b.w;
    out[i] = v;
}

// ---------------- GEMM: A(M,512) bf16 x Bt(512,512) bf16 (N,K) ----------------
// 256x256 block tile, BK=64, 8 waves (2M x 4N), per-wave output 128x64
// (8x4 frags of 16x16x32). LDS-BW per MFMA drops to 375B (8x A-reuse, 4x B-reuse)
// -> MFMA becomes the critical path (the 128^2/64x64-per-wave version was
// LDS-BW-matched: R2/R6/R8 pipeline depth experiments all landed ~0).
// Sync skeleton = the R6/R8-validated one: prologue stage -> per-iter
// [stage(next); vmcnt(8); barrier; COMPUTE; barrier]. A+B dbuf, 128KB LDS,
// 1 block/CU (2 waves/SIMD). vmcnt ledger: steady queue at wait =
// [A(t),B(t),A(t+1),B(t+1)] = 16 -> vmcnt(8) drains exactly tile t.
// Same source-side XOR swizzle + swizzled reads (conflicts=0 verified R5-R8).
// Grid 256 = 128 row-tiles x 2 col-tiles; XCD remap: 16 rows x 2 cols per XCD.
// FUSE=false: out bf16 (Bu). FUSE=true: out f32 = acc + D[col]*Ubf[o].
template<bool FUSE>
__global__ __launch_bounds__(512, 2)
void gemm_bt_kernel(const __bf16* __restrict__ A, const __bf16* __restrict__ Bt,
                    void* __restrict__ CoutV, const float* __restrict__ Dvec,
                    const __bf16* __restrict__ Ubf) {
    const int K = NP2, N = NP2;
    __shared__ __align__(16) __bf16 As[2][256 * 64];   // 64 KB
    __shared__ __align__(16) __bf16 Bs[2][256 * 64];   // 64 KB
    const int t = threadIdx.x;
    const int l = t & 63;
    const int w = t >> 6;           // wave 0..7
    const int wr = w >> 2;          // 0..1  (M)
    const int wc = w & 3;           // 0..3  (N)
    // XCD-aware bijective remap: 256 blocks = 8 XCDs * 32 slots
    const int b    = blockIdx.x;
    const int n_sw = (b & 7) * 32 + (b >> 3);
    const int row0 = (n_sw >> 1) * 256;
    const int col0 = (n_sw & 1) * 256;
    const int lr = l & 15;
    const int lk = (l >> 4) * 8;
    f32x4 acc[8][4] = {};

    // Full tile = 4 gload_lds per thread (2048 16B-chunks / 512 threads),
    // contiguous dest per wave, swizzled SOURCE column (rule #21).
    auto STAGE_A = [&](int buf, int k0) {
#pragma unroll
        for (int i = 0; i < 4; ++i) {
            int off = i * 512 + t;          // [0,2048)
            int r  = off >> 3;              // row 0..255
            int ce = ((off & 7) ^ (r & 7)) * 8;
            gload_lds16(A + (size_t)(row0 + r) * K + (k0 + ce), &As[buf][off * 8]);
        }
    };
    auto STAGE_B = [&](int buf, int k0) {
#pragma unroll
        for (int i = 0; i < 4; ++i) {
            int off = i * 512 + t;
            int r  = off >> 3;
            int ce = ((off & 7) ^ (r & 7)) * 8;
            gload_lds16(Bt + (size_t)(col0 + r) * K + (k0 + ce), &Bs[buf][off * 8]);
        }
    };

    auto COMPUTE = [&](int buf) {
#pragma unroll
        for (int kk = 0; kk < 64; kk += 32) {
            bf16x8 a[8], b2[4];
            const int ls = (kk + lk) >> 3;
#pragma unroll
            for (int m = 0; m < 8; ++m) {
                int row = wr * 128 + m * 16 + lr;
                a[m] = *reinterpret_cast<const bf16x8*>(&As[buf][row * 64 + ((ls ^ (row & 7)) << 3)]);
            }
#pragma unroll
            for (int n = 0; n < 4; ++n) {
                int row = wc * 64 + n * 16 + lr;
                b2[n] = *reinterpret_cast<const bf16x8*>(&Bs[buf][row * 64 + ((ls ^ (row & 7)) << 3)]);
            }
            __builtin_amdgcn_s_setprio(1);
#pragma unroll
            for (int m = 0; m < 8; ++m)
#pragma unroll
                for (int n = 0; n < 4; ++n)
                    acc[m][n] = __builtin_amdgcn_mfma_f32_16x16x32_bf16(a[m], b2[n], acc[m][n], 0, 0, 0);
            __builtin_amdgcn_s_setprio(0);
        }
    };

    // prologue: tile 0 in flight (8 loads)
    STAGE_A(0, 0);
    STAGE_B(0, 0);
#pragma unroll
    for (int ks = 0; ks < 8; ++ks) {
        if (ks + 1 < 8) {
            STAGE_A((ks + 1) & 1, (ks + 1) * 64);   // queue 16
            STAGE_B((ks + 1) & 1, (ks + 1) * 64);
            asm volatile("s_waitcnt vmcnt(8)" ::: "memory");   // drain tile ks
        } else {
            asm volatile("s_waitcnt vmcnt(0)" ::: "memory");
        }
        __builtin_amdgcn_s_barrier();           // tile ks staged by ALL waves
        __builtin_amdgcn_sched_barrier(0);
        COMPUTE(ks & 1);
        __builtin_amdgcn_sched_barrier(0);
        __builtin_amdgcn_s_barrier();           // all waves done reading bufs of tile ks
    }

    const int lg = (l >> 4) * 4;
#pragma unroll
    for (int m = 0; m < 8; ++m) {
#pragma unroll
        for (int n = 0; n < 4; ++n) {
            int col = col0 + wc * 64 + n * 16 + lr;
#pragma unroll
            for (int j = 0; j < 4; ++j) {
                int row = row0 + wr * 128 + m * 16 + lg + j;
                size_t o = (size_t)row * N + col;
                if (FUSE) {
                    ((float*)CoutV)[o] = acc[m][n][j] + Dvec[col] * (float)Ubf[o];
                } else {
                    ((__bf16*)CoutV)[o] = (__bf16)acc[m][n][j];
                }
            }
        }
    }
}

// ---------------- chunked scan (Bu is bf16) ----------------
// Level 0: per-chunk (32 steps) totals F[g], g in [0,1024)
__global__ void scanA_kernel(const __bf16* __restrict__ Bu, const float* __restrict__ par,
                             float* __restrict__ Fr, float* __restrict__ Fi) {
    int g = blockIdx.x;
    int p = threadIdx.x;
    float ar = par[p], ai = par[256 + p];
    const __bf16* bu = Bu + (size_t)g * CHUNK * NP2;
    float xr = 0.f, xi = 0.f;
#pragma unroll 4
    for (int i = 0; i < CHUNK; ++i) {
        float br = (float)bu[i * NP2 + p];
        float bi = (float)bu[i * NP2 + 256 + p];
        float nr = fmaf(ar, xr, fmaf(-ai, xi, br));
        float ni = fmaf(ar, xi, fmaf( ai, xr, bi));
        xr = nr; xi = ni;
    }
    Fr[g * 256 + p] = xr;
    Fi[g * 256 + p] = xi;
}

// Level 1: 32 blocks; block s scans its 32 chunks. Writes within-super exclusive
// prefixes l[g] and super-chunk totals T[s].
__global__ void scanB1_kernel(const float* __restrict__ Fr, const float* __restrict__ Fi,
                              const float* __restrict__ par,
                              float* __restrict__ Lr, float* __restrict__ Li,
                              float* __restrict__ Tr, float* __restrict__ Ti) {
    int s = blockIdx.x;
    int p = threadIdx.x;
    float pr = par[1024 + p], pi = par[1280 + p];   // Lbar^32
    float er = 0.f, ei = 0.f;
    int base = s * 32;
#pragma unroll
    for (int j = 0; j < 32; ++j) {
        int g = base + j;
        Lr[g * 256 + p] = er;
        Li[g * 256 + p] = ei;
        float fr = Fr[g * 256 + p], fi = Fi[g * 256 + p];
        float nr = fmaf(pr, er, fmaf(-pi, ei, fr));
        float ni = fmaf(pr, ei, fmaf( pi, er, fi));
        er = nr; ei = ni;
    }
    Tr[s * 256 + p] = er;
    Ti[s * 256 + p] = ei;
}

// Level 2: 1 block, serial exclusive scan over 32 super-chunk totals with Lbar^1024.
__global__ void scanB2_kernel(const float* __restrict__ Tr, const float* __restrict__ Ti,
                              const float* __restrict__ par,
                              float* __restrict__ Er, float* __restrict__ Ei) {
    int p = threadIdx.x;
    float ldr = par[1536 + p], ldi = par[1792 + p];
    float e  = expf(1024.0f * ldr);
    float ph = 1024.0f * ldi;
    float qr = e * cosf(ph), qi = e * sinf(ph);     // Lbar^1024
    float er = 0.f, ei = 0.f;
#pragma unroll
    for (int s = 0; s < NSUPER; ++s) {
        Er[s * 256 + p] = er;
        Ei[s * 256 + p] = ei;
        float fr = Tr[s * 256 + p], fi = Ti[s * 256 + p];
        float nr = fmaf(qr, er, fmaf(-qi, ei, fr));
        float ni = fmaf(qr, ei, fmaf( qi, er, fi));
        er = nr; ei = ni;
    }
}

// Final: per-chunk replay with carry = Lbar^(32k) * E[s] + l[g]; writes xs (bf16).
__global__ void scanC_kernel(const __bf16* __restrict__ Bu, const float* __restrict__ par,
                             const float* __restrict__ Lr, const float* __restrict__ Li,
                             const float* __restrict__ Er, const float* __restrict__ Ei,
                             __bf16* __restrict__ xs) {
    int g = blockIdx.x;
    int p = threadIdx.x;
    int s = g >> 5, k = g & 31;
    float ar = par[p], ai = par[256 + p];
    float ldr = par[1536 + p], ldi = par[1792 + p];
    float kk = (float)(32 * k);
    float e  = expf(kk * ldr);
    float ph = kk * ldi;
    float qr = e * cosf(ph), qi = e * sinf(ph);     // Lbar^(32k)
    float er = Er[s * 256 + p], ei = Ei[s * 256 + p];
    float lr0 = Lr[g * 256 + p], li0 = Li[g * 256 + p];
    float xr = fmaf(qr, er, fmaf(-qi, ei, lr0));
    float xi = fmaf(qr, ei, fmaf( qi, er, li0));
    const __bf16* bu = Bu + (size_t)g * CHUNK * NP2;
    __bf16* xo = xs + (size_t)g * CHUNK * NP2;
#pragma unroll 4
    for (int i = 0; i < CHUNK; ++i) {
        float br = (float)bu[i * NP2 + p];
        float bi = (float)bu[i * NP2 + 256 + p];
        float nr = fmaf(ar, xr, fmaf(-ai, xi, br));
        float ni = fmaf(ar, xi, fmaf( ai, xr, bi));
        xr = nr; xi = ni;
        xo[i * NP2 + p]       = (__bf16)xr;
        xo[i * NP2 + 256 + p] = (__bf16)xi;
    }
}

extern "C" void kernel_launch(void* const* d_in, const int* in_sizes, int n_in,
                              void* d_out, int out_size, void* d_ws, size_t ws_size,
                              hipStream_t stream) {
    const float* u   = (const float*)d_in[0];
    const float* Lre = (const float*)d_in[1];
    const float* Lim = (const float*)d_in[2];
    const float* Bre = (const float*)d_in[3];
    const float* Bim = (const float*)d_in[4];
    const float* Cre = (const float*)d_in[5];
    const float* Cim = (const float*)d_in[6];
    const float* Dv  = (const float*)d_in[7];
    const float* lst = (const float*)d_in[8];

    char* w = (char*)d_ws;
    size_t off = 0;
    float* par = (float*)(w + off);      off += 16 * 1024;
    __bf16* Btm = (__bf16*)(w + off);    off += (size_t)NP2 * NP2 * 2;      // 512 KB
    __bf16* Ctm = (__bf16*)(w + off);    off += (size_t)NP2 * NP2 * 2;      // 512 KB
    float* Fr  = (float*)(w + off);      off += (size_t)NCHUNK * 256 * 4;   // 1 MB
    float* Fi  = (float*)(w + off);      off += (size_t)NCHUNK * 256 * 4;
    float* Lr  = (float*)(w + off);      off += (size_t)NCHUNK * 256 * 4;
    float* Li  = (float*)(w + off);      off += (size_t)NCHUNK * 256 * 4;
    float* Tr  = (float*)(w + off);      off += (size_t)NSUPER * 256 * 4;   // 32 KB
    float* Ti  = (float*)(w + off);      off += (size_t)NSUPER * 256 * 4;
    float* Er  = (float*)(w + off);      off += (size_t)NSUPER * 256 * 4;
    float* Ei  = (float*)(w + off);      off += (size_t)NSUPER * 256 * 4;
    __bf16* Ubf = (__bf16*)(w + off);    off += (size_t)L_SEQ * H_DIM * 2;  // 32 MB (bf16 u)
    __bf16* Xs  = (__bf16*)(w + off);    off += (size_t)L_SEQ * NP2 * 2;    // 32 MB (xs)
    if (ws_size < off) return;  // fail loudly (output stays poisoned)

    // Bu: bf16 L x 2P (32 MB) in the lower half of d_out; GEMM2 overwrites
    // all of d_out (f32 output) afterwards.
    __bf16* Bu = (__bf16*)d_out;

    prep_kernel    <<<1,    256, 0, stream>>>(Lre, Lim, lst, par);
    build_BC_kernel<<<1024, 256, 0, stream>>>(Bre, Bim, par, Cre, Cim, Btm, Ctm);
    cast_u_kernel  <<<8192, 256, 0, stream>>>((const float4*)u, (bf16x8*)Ubf, L_SEQ * H_DIM / 8);
    gemm_bt_kernel<false><<<256, 512, 0, stream>>>(Ubf, Btm, (void*)Bu, nullptr, nullptr);
    scanA_kernel   <<<NCHUNK, 256, 0, stream>>>(Bu, par, Fr, Fi);
    scanB1_kernel  <<<NSUPER, 256, 0, stream>>>(Fr, Fi, par, Lr, Li, Tr, Ti);
    scanB2_kernel  <<<1,      256, 0, stream>>>(Tr, Ti, par, Er, Ei);
    scanC_kernel   <<<NCHUNK, 256, 0, stream>>>(Bu, par, Lr, Li, Er, Ei, Xs);
    gemm_bt_kernel<true><<<256, 512, 0, stream>>>(Xs, Ctm, d_out, Dv, Ubf);
}

// Round 10
// 98.175 us; speedup vs baseline: 1.0694x; 1.0694x over previous
//
#include <hip/hip_runtime.h>
#include <cstdint>
#include <cstddef>

typedef __bf16 bf16x8 __attribute__((ext_vector_type(8)));
typedef float f32x4 __attribute__((ext_vector_type(4)));

#define L_SEQ 32768
#define H_DIM 512
#define P_DIM 256
#define NP2   512      // 2P = K and N of both GEMMs
#define CHUNK 32
#define NCHUNK 1024    // L / CHUNK
#define NSUPER 32      // NCHUNK / 32

__device__ __forceinline__ void gload_lds16(const void* g, void* l) {
    __builtin_amdgcn_global_load_lds(
        (const __attribute__((address_space(1))) void*)g,
        (__attribute__((address_space(3))) void*)l,
        16, 0, 0);
}

// ---------------- fused setup: prep (block 0) | build B/C (blocks 1..1024) |
// cast u->bf16 (blocks 1025..9216). prep's par is NOT needed by the builders
// (coef computed inline; p is uniform per block -> scalar transcendentals).
// par layout (floats): [0]=Ar [256]=Ai [1024]=PowR(Lbar^32) [1280]=PowI
//                      [1536]=ldr [1792]=ldi
__global__ void setup_kernel(const float* __restrict__ Lre, const float* __restrict__ Lim,
                             const float* __restrict__ lstep,
                             const float* __restrict__ Bre, const float* __restrict__ Bim,
                             const float* __restrict__ Cre, const float* __restrict__ Cim,
                             const float4* __restrict__ uin,
                             float* __restrict__ par,
                             __bf16* __restrict__ Bt, __bf16* __restrict__ Ct,
                             bf16x8* __restrict__ Ubf) {
    int b = blockIdx.x;
    if (b == 0) {
        int p = threadIdx.x;
        float lr = fminf(Lre[p], -1e-4f);       // clip_eigs
        float li = Lim[p];
        float st = expf(lstep[p]);
        float ldr = lr * st;
        float ldi = li * st;
        float er = expf(ldr);
        par[p]        = er * cosf(ldi);         // Ar
        par[256 + p]  = er * sinf(ldi);         // Ai
        float e32  = expf((float)CHUNK * ldr);
        float ph32 = (float)CHUNK * ldi;
        par[1024 + p] = e32 * cosf(ph32);       // PowR = Re(Lbar^32)
        par[1280 + p] = e32 * sinf(ph32);       // PowI
        par[1536 + p] = ldr;
        par[1792 + p] = ldi;
    } else if (b <= 1024) {
        int bb = b - 1;
        if (bb < 512) {
            int idx = bb * 256 + threadIdx.x;   // [0, P*H)
            int p = idx >> 9;                   // uniform per block
            float lr = fminf(Lre[p], -1e-4f);
            float li = Lim[p];
            float st = expf(lstep[p]);
            float er = expf(lr * st);
            float ar = er * cosf(li * st);
            float ai = er * sinf(li * st);
            float den = lr * lr + li * li;
            float mr = ar - 1.0f, mi = ai;
            float cr = (mr * lr + mi * li) / den;   // coef = (Lbar-1)/Lambda
            float ci = (mi * lr - mr * li) / den;
            float br = Bre[idx], bi = Bim[idx];
            int h = idx & 511;
            Bt[(size_t)p * NP2 + h]         = (__bf16)(cr * br - ci * bi);
            Bt[(size_t)(256 + p) * NP2 + h] = (__bf16)(cr * bi + ci * br);
        } else {
            int idx = (bb - 512) * 256 + threadIdx.x;   // [0, H*P)
            int h = idx >> 8;
            int q = idx & 255;
            Ct[(size_t)h * NP2 + q]       = (__bf16)( 2.0f * Cre[idx]);
            Ct[(size_t)h * NP2 + 256 + q] = (__bf16)(-2.0f * Cim[idx]);
        }
    } else {
        int i = (b - 1025) * 256 + threadIdx.x;     // [0, L*H/8)
        float4 a = uin[2 * i], c = uin[2 * i + 1];
        bf16x8 v;
        v[0] = (__bf16)a.x; v[1] = (__bf16)a.y; v[2] = (__bf16)a.z; v[3] = (__bf16)a.w;
        v[4] = (__bf16)c.x; v[5] = (__bf16)c.y; v[6] = (__bf16)c.z; v[7] = (__bf16)c.w;
        Ubf[i] = v;
    }
}

// ---------------- GEMM: A(M,512) bf16 x Bt(512,512) bf16 (N,K), 128x128 tile, BK=64 ----------------
// R8-validated version (best measured). Deep counted pipeline, full-tile staging
// (gload_lds needs linear contiguous dest). A: 3 buffers (2 ahead, HBM latency);
// B: 2 buffers (1 ahead, L2-resident). LDS 80KB -> 2 blocks/CU.
// vmcnt ledger (4 loads/unit; per-iter issue B(t+1), A(t+2)): steady queue at
// wait = [A(t),B(t),A(t+1),B(t+1),A(t+2)] = 20 -> vmcnt(12) drains A(t)+B(t).
// ks=6 -> vmcnt(8); ks=7 -> vmcnt(0). Overwrites fenced by trailing barrier.
// Full 8-slot XOR source-side swizzle (rule #21) + swizzled reads (conflicts=0).
// FUSE=false: out bf16 (Bu). FUSE=true: out f32 = acc + D[col]*Ubf[o].
template<bool FUSE>
__global__ __launch_bounds__(256)
void gemm_bt_kernel(const __bf16* __restrict__ A, const __bf16* __restrict__ Bt,
                    void* __restrict__ CoutV, const float* __restrict__ Dvec,
                    const __bf16* __restrict__ Ubf) {
    const int K = NP2, N = NP2;
    __shared__ __align__(16) __bf16 As[3][128 * 64];
    __shared__ __align__(16) __bf16 Bs[2][128 * 64];
    const int t = threadIdx.x;
    const int l = t & 63;
    const int w = t >> 6;
    const int wr = w >> 1, wc = w & 1;
    // XCD-aware bijective remap: 1024 blocks = 8 XCDs * 128 slots
    const int b    = blockIdx.x;
    const int n_sw = (b & 7) * 128 + (b >> 3);
    const int row0 = (n_sw >> 2) * 128;
    const int col0 = (n_sw & 3) * 128;
    const int lr = l & 15;
    const int lk = (l >> 4) * 8;
    f32x4 acc[4][4] = {};

    auto STAGE_A = [&](int buf, int k0) {
#pragma unroll
        for (int i = 0; i < 4; ++i) {
            int off = i * 256 + t;
            int r  = off >> 3;
            int ce = ((off & 7) ^ (r & 7)) * 8;
            gload_lds16(A + (size_t)(row0 + r) * K + (k0 + ce), &As[buf][off * 8]);
        }
    };
    auto STAGE_B = [&](int buf, int k0) {
#pragma unroll
        for (int i = 0; i < 4; ++i) {
            int off = i * 256 + t;
            int r  = off >> 3;
            int ce = ((off & 7) ^ (r & 7)) * 8;
            gload_lds16(Bt + (size_t)(col0 + r) * K + (k0 + ce), &Bs[buf][off * 8]);
        }
    };

    auto COMPUTE = [&](int ba, int bb) {
#pragma unroll
        for (int kk = 0; kk < 64; kk += 32) {
            bf16x8 a[4], b2[4];
            const int ls = (kk + lk) >> 3;
#pragma unroll
            for (int m = 0; m < 4; ++m) {
                int row = wr * 64 + m * 16 + lr;
                a[m] = *reinterpret_cast<const bf16x8*>(&As[ba][row * 64 + ((ls ^ (row & 7)) << 3)]);
            }
#pragma unroll
            for (int n = 0; n < 4; ++n) {
                int row = wc * 64 + n * 16 + lr;
                b2[n] = *reinterpret_cast<const bf16x8*>(&Bs[bb][row * 64 + ((ls ^ (row & 7)) << 3)]);
            }
            __builtin_amdgcn_s_setprio(1);
#pragma unroll
            for (int m = 0; m < 4; ++m)
#pragma unroll
                for (int n = 0; n < 4; ++n)
                    acc[m][n] = __builtin_amdgcn_mfma_f32_16x16x32_bf16(a[m], b2[n], acc[m][n], 0, 0, 0);
            __builtin_amdgcn_s_setprio(0);
        }
    };

    // prologue: A0, B0, A1  (queue = 12)
    STAGE_A(0, 0);
    STAGE_B(0, 0);
    STAGE_A(1, 64);
#pragma unroll
    for (int ks = 0; ks < 8; ++ks) {
        if (ks + 1 < 8) STAGE_B((ks + 1) & 1, (ks + 1) * 64);
        if (ks + 2 < 8) STAGE_A((ks + 2) % 3, (ks + 2) * 64);
        if (ks <= 5)      { asm volatile("s_waitcnt vmcnt(12)" ::: "memory"); }
        else if (ks == 6) { asm volatile("s_waitcnt vmcnt(8)"  ::: "memory"); }
        else              { asm volatile("s_waitcnt vmcnt(0)"  ::: "memory"); }
        __builtin_amdgcn_s_barrier();           // A(ks),B(ks) staged by ALL waves
        __builtin_amdgcn_sched_barrier(0);
        COMPUTE(ks % 3, ks & 1);
        __builtin_amdgcn_sched_barrier(0);
        __builtin_amdgcn_s_barrier();           // all waves done reading bufs of tile ks
    }

    const int lg = (l >> 4) * 4;
#pragma unroll
    for (int m = 0; m < 4; ++m) {
#pragma unroll
        for (int n = 0; n < 4; ++n) {
            int col = col0 + wc * 64 + n * 16 + lr;
#pragma unroll
            for (int j = 0; j < 4; ++j) {
                int row = row0 + wr * 64 + m * 16 + lg + j;
                size_t o = (size_t)row * N + col;
                if (FUSE) {
                    ((float*)CoutV)[o] = acc[m][n][j] + Dvec[col] * (float)Ubf[o];
                } else {
                    ((__bf16*)CoutV)[o] = (__bf16)acc[m][n][j];
                }
            }
        }
    }
}

// ---------------- chunked scan (Bu is bf16) ----------------
// Level 0: per-chunk (32 steps) totals F[g], g in [0,1024)
__global__ void scanA_kernel(const __bf16* __restrict__ Bu, const float* __restrict__ par,
                             float* __restrict__ Fr, float* __restrict__ Fi) {
    int g = blockIdx.x;
    int p = threadIdx.x;
    float ar = par[p], ai = par[256 + p];
    const __bf16* bu = Bu + (size_t)g * CHUNK * NP2;
    float xr = 0.f, xi = 0.f;
#pragma unroll 4
    for (int i = 0; i < CHUNK; ++i) {
        float br = (float)bu[i * NP2 + p];
        float bi = (float)bu[i * NP2 + 256 + p];
        float nr = fmaf(ar, xr, fmaf(-ai, xi, br));
        float ni = fmaf(ar, xi, fmaf( ai, xr, bi));
        xr = nr; xi = ni;
    }
    Fr[g * 256 + p] = xr;
    Fi[g * 256 + p] = xi;
}

// Level 1: 32 blocks; block s scans its 32 chunks. Writes within-super exclusive
// prefixes l[g] and super-chunk totals T[s].
__global__ void scanB1_kernel(const float* __restrict__ Fr, const float* __restrict__ Fi,
                              const float* __restrict__ par,
                              float* __restrict__ Lr, float* __restrict__ Li,
                              float* __restrict__ Tr, float* __restrict__ Ti) {
    int s = blockIdx.x;
    int p = threadIdx.x;
    float pr = par[1024 + p], pi = par[1280 + p];   // Lbar^32
    float er = 0.f, ei = 0.f;
    int base = s * 32;
#pragma unroll
    for (int j = 0; j < 32; ++j) {
        int g = base + j;
        Lr[g * 256 + p] = er;
        Li[g * 256 + p] = ei;
        float fr = Fr[g * 256 + p], fi = Fi[g * 256 + p];
        float nr = fmaf(pr, er, fmaf(-pi, ei, fr));
        float ni = fmaf(pr, ei, fmaf( pi, er, fi));
        er = nr; ei = ni;
    }
    Tr[s * 256 + p] = er;
    Ti[s * 256 + p] = ei;
}

// Final: per-chunk replay. Carry computed fully inline:
//   E[s] = exclusive scan of T with Lbar^1024 (<=31 L2 reads + FMA chain,
//   exactly scanB2's math — that kernel is deleted);
//   carry = Lbar^(32k) * E[s] + L[g].  Writes xs (bf16).
__global__ void scanC_kernel(const __bf16* __restrict__ Bu, const float* __restrict__ par,
                             const float* __restrict__ Lr, const float* __restrict__ Li,
                             const float* __restrict__ Tr, const float* __restrict__ Ti,
                             __bf16* __restrict__ xs) {
    int g = blockIdx.x;
    int p = threadIdx.x;
    int s = g >> 5, k = g & 31;
    float ar = par[p], ai = par[256 + p];
    float ldr = par[1536 + p], ldi = par[1792 + p];
    // Lbar^1024
    float e1  = expf(1024.0f * ldr);
    float ph1 = 1024.0f * ldi;
    float q1r = e1 * cosf(ph1), q1i = e1 * sinf(ph1);
    // E[s]: exclusive scan over super-chunk totals
    float er = 0.f, ei = 0.f;
    for (int s2 = 0; s2 < s; ++s2) {
        float fr = Tr[s2 * 256 + p], fi = Ti[s2 * 256 + p];
        float nr = fmaf(q1r, er, fmaf(-q1i, ei, fr));
        float ni = fmaf(q1r, ei, fmaf( q1i, er, fi));
        er = nr; ei = ni;
    }
    // Lbar^(32k)
    float kk = (float)(32 * k);
    float e  = expf(kk * ldr);
    float ph = kk * ldi;
    float qr = e * cosf(ph), qi = e * sinf(ph);
    float lr0 = Lr[g * 256 + p], li0 = Li[g * 256 + p];
    float xr = fmaf(qr, er, fmaf(-qi, ei, lr0));
    float xi = fmaf(qr, ei, fmaf( qi, er, li0));
    const __bf16* bu = Bu + (size_t)g * CHUNK * NP2;
    __bf16* xo = xs + (size_t)g * CHUNK * NP2;
#pragma unroll 4
    for (int i = 0; i < CHUNK; ++i) {
        float br = (float)bu[i * NP2 + p];
        float bi = (float)bu[i * NP2 + 256 + p];
        float nr = fmaf(ar, xr, fmaf(-ai, xi, br));
        float ni = fmaf(ar, xi, fmaf( ai, xr, bi));
        xr = nr; xi = ni;
        xo[i * NP2 + p]       = (__bf16)xr;
        xo[i * NP2 + 256 + p] = (__bf16)xi;
    }
}

extern "C" void kernel_launch(void* const* d_in, const int* in_sizes, int n_in,
                              void* d_out, int out_size, void* d_ws, size_t ws_size,
                              hipStream_t stream) {
    const float* u   = (const float*)d_in[0];
    const float* Lre = (const float*)d_in[1];
    const float* Lim = (const float*)d_in[2];
    const float* Bre = (const float*)d_in[3];
    const float* Bim = (const float*)d_in[4];
    const float* Cre = (const float*)d_in[5];
    const float* Cim = (const float*)d_in[6];
    const float* Dv  = (const float*)d_in[7];
    const float* lst = (const float*)d_in[8];

    char* w = (char*)d_ws;
    size_t off = 0;
    float* par = (float*)(w + off);      off += 16 * 1024;
    __bf16* Btm = (__bf16*)(w + off);    off += (size_t)NP2 * NP2 * 2;      // 512 KB
    __bf16* Ctm = (__bf16*)(w + off);    off += (size_t)NP2 * NP2 * 2;      // 512 KB
    float* Fr  = (float*)(w + off);      off += (size_t)NCHUNK * 256 * 4;   // 1 MB
    float* Fi  = (float*)(w + off);      off += (size_t)NCHUNK * 256 * 4;
    float* Lr  = (float*)(w + off);      off += (size_t)NCHUNK * 256 * 4;
    float* Li  = (float*)(w + off);      off += (size_t)NCHUNK * 256 * 4;
    float* Tr  = (float*)(w + off);      off += (size_t)NSUPER * 256 * 4;   // 32 KB
    float* Ti  = (float*)(w + off);      off += (size_t)NSUPER * 256 * 4;
    __bf16* Ubf = (__bf16*)(w + off);    off += (size_t)L_SEQ * H_DIM * 2;  // 32 MB (bf16 u)
    __bf16* Xs  = (__bf16*)(w + off);    off += (size_t)L_SEQ * NP2 * 2;    // 32 MB (xs)
    if (ws_size < off) return;  // fail loudly (output stays poisoned)

    // Bu: bf16 L x 2P (32 MB) in the lower half of d_out; GEMM2 overwrites
    // all of d_out (f32 output) afterwards.
    __bf16* Bu = (__bf16*)d_out;

    setup_kernel  <<<9217, 256, 0, stream>>>(Lre, Lim, lst, Bre, Bim, Cre, Cim,
                                             (const float4*)u, par, Btm, Ctm, (bf16x8*)Ubf);
    gemm_bt_kernel<false><<<1024, 256, 0, stream>>>(Ubf, Btm, (void*)Bu, nullptr, nullptr);
    scanA_kernel  <<<NCHUNK, 256, 0, stream>>>(Bu, par, Fr, Fi);
    scanB1_kernel <<<NSUPER, 256, 0, stream>>>(Fr, Fi, par, Lr, Li, Tr, Ti);
    scanC_kernel  <<<NCHUNK, 256, 0, stream>>>(Bu, par, Lr, Li, Tr, Ti, Xs);
    gemm_bt_kernel<true><<<1024, 256, 0, stream>>>(Xs, Ctm, d_out, Dv, Ubf);
}